// Round 10
// baseline (2379.855 us; speedup 1.0000x reference)
//
#include <hip/hip_runtime.h>
#include <stdint.h>

// DecoderRNN: B=256, NSTEPS=128, I=128, H=1024, V=1024, teacher-forced GRU.
// Round 10: persistent kernel, BARRIER-FREE K-loop. Each wave stages its own
// 16 h-rows (coalesced global_load_lds, sc0|sc1) into its own LDS quarter ->
// own vmcnt ledger covers all its reads -> no s_barrier, waves drift freely.
// Per-block monotone counters (atomicAdd x4/step); one poll+drain per step.
//   LDS 160KB: [0,64K) W12 z,n; [64K,96K) Wout; [96K,160K) dbuf 4x16KB
//   (each buffer wave-partitioned into 4KB quarters).
//   W_hh gate-r slice in registers (32 bf16x8). E/tok prefetched 1 step ahead.

#define NSTEP 128

typedef unsigned short u16;
typedef unsigned int u32;
typedef __attribute__((ext_vector_type(8))) short bf16x8;
typedef __attribute__((ext_vector_type(4))) int i32x4;
typedef __attribute__((ext_vector_type(4))) float f32x4;

typedef __attribute__((address_space(3))) void lds_void;
typedef const __attribute__((address_space(1))) void glb_void;
#define GLD16(g, l) __builtin_amdgcn_global_load_lds((glb_void*)(g), (lds_void*)(l), 16, 0, 0)
// CPol gfx940+: SC0=1, SC1=16 -> 17 (coherent, bypass stale L1/L2)
#define GLD16C(g, l) __builtin_amdgcn_global_load_lds((glb_void*)(g), (lds_void*)(l), 16, 0, 17)
#define CFENCE() asm volatile("" ::: "memory")

#if __has_builtin(__builtin_amdgcn_exp2f)
#define EXP2(x) __builtin_amdgcn_exp2f(x)
#else
#define EXP2(x) exp2f(x)
#endif
#if __has_builtin(__builtin_amdgcn_rcpf)
#define RCP(x) __builtin_amdgcn_rcpf(x)
#else
#define RCP(x) (1.0f / (x))
#endif

__device__ __forceinline__ u16 f2bf(float f) {
    u32 u = __float_as_uint(f);
    u = (u + 0x7FFFu + ((u >> 16) & 1u)) >> 16;
    return (u16)u;
}
__device__ __forceinline__ float fsigmoid(float x) {
    return RCP(1.f + EXP2(x * -1.44269504f));
}
__device__ __forceinline__ float ftanh(float x) {
    x = fminf(fmaxf(x, -18.f), 18.f);
    float t = EXP2(x * 2.88539008f);
    return (t - 1.f) * RCP(t + 1.f);
}

// ---- exact-count asm memory ops (ledger discipline) -------------------------
__device__ __forceinline__ void gloadf(float& d, const float* a) { // 1 event
    asm volatile("global_load_dword %0, %1, off" : "=&v"(d) : "v"(a) : "memory");
}
__device__ __forceinline__ void gloadi4(i32x4& d, const int* a) { // 1 event
    asm volatile("global_load_dwordx4 %0, %1, off" : "=&v"(d) : "v"(a) : "memory");
}
__device__ __forceinline__ void gloadu32c(u32& d, const u32* a) { // 1 event, coherent
    asm volatile("global_load_dword %0, %1, off sc0 sc1" : "=&v"(d) : "v"(a) : "memory");
}
__device__ __forceinline__ void gstore_short_c(u16* a, u32 v) { // 1 event, coherent
    asm volatile("global_store_short %0, %1, off sc0 sc1" ::"v"(a), "v"(v) : "memory");
}
__device__ __forceinline__ void gstoref(float* a, float v) { // 1 event
    asm volatile("global_store_dword %0, %1, off" ::"v"(a), "v"(v) : "memory");
}

// ---- elementwise fp32 -> bf16 cast (1024 columns per row) ------------------
__global__ void cast_k(const float* __restrict__ src, int ld, int off, int relu,
                       u16* __restrict__ dst, int n) {
    for (int i = blockIdx.x * blockDim.x + threadIdx.x; i < n; i += gridDim.x * blockDim.x) {
        int row = i >> 10, col = i & 1023;
        float v = src[(long)row * ld + off + col];
        if (relu) v = fmaxf(v, 0.f);
        dst[i] = f2bf(v);
    }
}

// ---- small fp32 GEMM: C[b][n] = z[b]·W[n, off:off+128] + bias[n] (+bias2) --
__global__ void smallgemm_k(const float* __restrict__ z, const float* __restrict__ W,
                            int ldw, int off, const float* __restrict__ bias,
                            const float* __restrict__ bias2, int n2max,
                            float* __restrict__ C, u16* __restrict__ Cbf, int N) {
    int n = blockIdx.x;
    int b = threadIdx.x;
    float acc = bias[n] + ((bias2 && n < n2max) ? bias2[n] : 0.f);
    const float* zr = z + b * 128;
    const float* wr = W + (long)n * ldw + off;
#pragma unroll 8
    for (int k = 0; k < 128; ++k) acc += zr[k] * wr[k];
    C[b * N + n] = acc;
    if (Cbf) Cbf[b * N + n] = f2bf(acc);
}

// ---- E table GEMM: E[v][n] = relu(embed)[v]·Wihh[n]  (M=1024,N=3072,K=1024)
__global__ __launch_bounds__(256) void egemm_k(const u16* __restrict__ A,
                                               const u16* __restrict__ W,
                                               float* __restrict__ C) {
    __shared__ __align__(16) u16 lds[2][160 * 64];
    int tid = threadIdx.x, lane = tid & 63, wv = tid >> 6;
    int r0 = (blockIdx.x & 31) * 32;
    int n0 = (blockIdx.x >> 5) * 128;

    f32x4 acc[2][2];
#pragma unroll
    for (int m = 0; m < 2; ++m)
#pragma unroll
        for (int n = 0; n < 2; ++n) acc[m][n] = (f32x4){0.f, 0.f, 0.f, 0.f};

    auto stage = [&](int k0, int bufi) {
#pragma unroll
        for (int r = 0; r < 5; ++r) {
            int L = r * 256 + tid;
            int row = L >> 3;
            int c4 = (L & 7) ^ (row & 7);
            const u16* src = (row < 32)
                                 ? A + (long)(r0 + row) * 1024 + k0 + c4 * 8
                                 : W + (long)(n0 + row - 32) * 1024 + k0 + c4 * 8;
            GLD16(src, &lds[bufi][L * 8]);
        }
    };
    stage(0, 0);
    stage(64, 1);
    for (int it = 0; it < 16; ++it) {
        if (it < 15) asm volatile("s_waitcnt vmcnt(5)" ::: "memory");
        else         asm volatile("s_waitcnt vmcnt(0)" ::: "memory");
        __builtin_amdgcn_s_barrier();
        const char* base = (const char*)&lds[it & 1][0];
        bf16x8 af[2][2], bfr[2][2];
#pragma unroll
        for (int ks = 0; ks < 2; ++ks)
#pragma unroll
            for (int q = 0; q < 2; ++q) {
                int kb = ks * 64 + ((lane >> 4) << 4);
                int rowa = q * 16 + (lane & 15);
                af[ks][q] = *(const bf16x8*)(base + rowa * 128 + (kb ^ ((rowa & 7) << 4)));
                int rowb = 32 + wv * 32 + q * 16 + (lane & 15);
                bfr[ks][q] = *(const bf16x8*)(base + rowb * 128 + (kb ^ ((rowb & 7) << 4)));
            }
#pragma unroll
        for (int ks = 0; ks < 2; ++ks)
#pragma unroll
            for (int m = 0; m < 2; ++m)
#pragma unroll
                for (int n = 0; n < 2; ++n)
                    acc[m][n] = __builtin_amdgcn_mfma_f32_16x16x32_bf16(af[ks][m], bfr[ks][n],
                                                                        acc[m][n], 0, 0, 0);
        asm volatile("s_waitcnt lgkmcnt(0)" ::: "memory");
        __builtin_amdgcn_s_barrier();
        if (it + 2 < 16) stage((it + 2) * 64, it & 1);
    }
#pragma unroll
    for (int m = 0; m < 2; ++m)
#pragma unroll
        for (int n = 0; n < 2; ++n)
#pragma unroll
            for (int r = 0; r < 4; ++r) {
                int row = r0 + m * 16 + ((lane >> 4) << 2) + r;
                int col = n0 + wv * 32 + n * 16 + (lane & 15);
                C[(long)row * 3072 + col] = acc[m][n][r];
            }
}

// ---- persistent decoder: barrier-free K-loop --------------------------------
__global__ __launch_bounds__(256, 1) void decoder_k(
    const u16* __restrict__ Whh,    // [3072][1024] bf16
    const u16* __restrict__ Wout,   // [1024][1024] bf16
    const float* __restrict__ E,    // [1024][3072]
    const float* __restrict__ Zih2, // [256][3072]  (b_ih folded; +b_hh for r,z)
    const float* __restrict__ Zout, // [256][1024]  (out_b folded)
    const float* __restrict__ bhh,  // [3072]
    const int* __restrict__ toks,   // [128][256]
    const float* __restrict__ h0f,  // [256][1024] fp32
    u16* __restrict__ Hx,           // [2][256][1024] bf16 ping-pong
    float* __restrict__ out,        // [256][128][1024]
    u32* __restrict__ cnt) {        // [256] per-block monotone counters
    __shared__ __align__(16) char L[163840];
    const int tid = threadIdx.x, lane = tid & 63, wv = tid >> 6;
    const int bid = blockIdx.x;
    const int rB = bid >> 6; // rows rB*64..+63
    const int c = bid & 63;  // cols c*16..+15

    // ---- startup: gate-r -> temp(dbuf) -> regs; gates z,n -> W12; Wout ----
#pragma unroll
    for (int r = 0; r < 8; ++r) {
        int l = r * 256 + tid, row = l >> 7, ck = (l & 127) ^ (row & 15);
        GLD16(Whh + (long)(c * 16 + row) * 1024 + ck * 8, &L[98304 + l * 16]);
    }
    asm volatile("s_waitcnt vmcnt(0)" ::: "memory");
    __syncthreads();
    bf16x8 w0[32]; // gate-r B-fragments [it*4+ks], persistent in VGPRs
#pragma unroll
    for (int it = 0; it < 8; ++it)
#pragma unroll
        for (int ks = 0; ks < 4; ++ks) {
            int row = lane & 15, kc = it * 16 + ks * 4 + (lane >> 4);
            w0[it * 4 + ks] = *(const bf16x8*)(L + 98304 + row * 2048 + ((kc ^ row) << 4));
        }
    asm volatile("s_waitcnt lgkmcnt(0)" ::: "memory");
    __syncthreads();
#pragma unroll
    for (int r = 0; r < 16; ++r) {
        int l = r * 256 + tid, row = l >> 7, ck = (l & 127) ^ (row & 15);
        GLD16(Whh + (long)((1 + (row >> 4)) * 1024 + c * 16 + (row & 15)) * 1024 + ck * 8,
              &L[l * 16]);
    }
#pragma unroll
    for (int r = 0; r < 8; ++r) {
        int l = r * 256 + tid, row = l >> 7, ck = (l & 127) ^ (row & 15);
        GLD16(Wout + (long)(c * 16 + row) * 1024 + ck * 8, &L[65536 + l * 16]);
    }
    asm volatile("s_waitcnt vmcnt(0)" ::: "memory");
    __syncthreads(); // weights read-only from here; NO further barriers

    // ---- per-thread step-invariant state ----
    const int bbase = rB * 64 + wv * 16 + ((lane >> 4) << 2); // rows bbase..+3
    const int j = c * 16 + (lane & 15);
    const float bhn = bhh[2048 + j];
    float hprev[4], zi0[4], zi1[4], zi2[4], zo[4];
#pragma unroll
    for (int r = 0; r < 4; ++r) {
        int b = bbase + r;
        hprev[r] = h0f[b * 1024 + j];
        zi0[r] = Zih2[(long)b * 3072 + j];
        zi1[r] = Zih2[(long)b * 3072 + 1024 + j];
        zi2[r] = Zih2[(long)b * 3072 + 2048 + j];
        zo[r] = Zout[b * 1024 + j];
    }
    const u32* cf = cnt + rB * 64; // 64 producer counters of this row-group
    // wave-local staging geometry: wave wv owns rows wv*16..+15; buffer quarter
    // at dbuf + buf*16384 + wv*4096. Instr r stages rows 4r..4r+3 (1KB contig).
    const int srow = rB * 64 + wv * 16; // global h-row base for this wave
    // prologue: E_cur for s=0 (tok = SOS = 0): 12 events, retired at iter0 wait
    float ec0[4], ec1[4], ec2[4];
#pragma unroll
    for (int r = 0; r < 4; ++r) {
        const float* eb = E + j;
        gloadf(ec0[r], eb);
        gloadf(ec1[r], eb + 1024);
        gloadf(ec2[r], eb + 2048);
    }

    for (int s = 0; s <= NSTEP; ++s) {
        // tok for step s+1 (value survives the poll drain in VGPRs)
        i32x4 tokv;
        if (s < NSTEP) gloadi4(tokv, toks + s * 256 + bbase);

        if (s >= 1) { // wait for all 64 producers of h_s (one poll+drain/step)
            const u32 tgt = 4u * (u32)s;
            while (true) {
                u32 v;
                gloadu32c(v, cf + lane);
                asm volatile("s_waitcnt vmcnt(0)" ::: "memory");
                __builtin_amdgcn_sched_barrier(0);
                if (__all(v >= tgt)) break;
                __builtin_amdgcn_s_sleep(1);
            }
        }

        const u16* hsrc = Hx + (size_t)(s & 1) * 262144;
        auto stage = [&](int ch) { // 4 events; wave-local rows only
            char* dst = L + 98304 + (ch & 3) * 16384 + wv * 4096;
            int k0 = ch * 128;
#pragma unroll
            for (int r = 0; r < 4; ++r) {
                int rl = 4 * r + (lane >> 4); // local row 0..15
                int ck = (lane & 15) ^ (rl & 15);
                GLD16C(hsrc + (long)(srow + rl) * 1024 + k0 + ck * 8, dst + r * 1024 + lane * 16);
            }
        };
        stage(0);
        stage(1);
        stage(2);
        CFENCE();

        f32x4 a0 = {0.f, 0.f, 0.f, 0.f}, a1 = a0, a2 = a0, aO = a0;
#pragma unroll
        for (int it = 0; it < 8; ++it) {
            if (it < 5) stage(it + 3);
            // ledger (stages only in flight): retire chunk it
            if (it < 5)       asm volatile("s_waitcnt vmcnt(12)" ::: "memory");
            else if (it == 5) asm volatile("s_waitcnt vmcnt(8)" ::: "memory");
            else if (it == 6) asm volatile("s_waitcnt vmcnt(4)" ::: "memory");
            else              asm volatile("s_waitcnt vmcnt(0)" ::: "memory");
            __builtin_amdgcn_sched_barrier(0); // rule 18: pin ds_reads below wait
            const char* Ab = L + 98304 + (it & 3) * 16384 + wv * 4096;
            bf16x8 af[4];
#pragma unroll
            for (int ks = 0; ks < 4; ++ks) { // own quarter: local row = lane&15
                int rl = lane & 15, kc = ks * 4 + (lane >> 4);
                af[ks] = *(const bf16x8*)(Ab + rl * 256 + ((kc ^ rl) << 4));
            }
#pragma unroll
            for (int ks = 0; ks < 4; ++ks) // gate r from registers
                a0 = __builtin_amdgcn_mfma_f32_16x16x32_bf16(af[ks], w0[it * 4 + ks],
                                                             a0, 0, 0, 0);
#pragma unroll
            for (int ks = 0; ks < 4; ++ks) { // gate z from W12
                int row = lane & 15, kc = it * 16 + ks * 4 + (lane >> 4);
                bf16x8 wg = *(const bf16x8*)(L + row * 2048 + ((kc ^ row) << 4));
                a1 = __builtin_amdgcn_mfma_f32_16x16x32_bf16(af[ks], wg, a1, 0, 0, 0);
            }
#pragma unroll
            for (int ks = 0; ks < 4; ++ks) { // gate n from W12
                int row = 16 + (lane & 15), kc = it * 16 + ks * 4 + (lane >> 4);
                bf16x8 wg = *(const bf16x8*)(L + row * 2048 + ((kc ^ (row & 15)) << 4));
                a2 = __builtin_amdgcn_mfma_f32_16x16x32_bf16(af[ks], wg, a2, 0, 0, 0);
            }
#pragma unroll
            for (int ks = 0; ks < 4; ++ks) { // OUT from WoutL
                int row = lane & 15, kc = it * 16 + ks * 4 + (lane >> 4);
                bf16x8 wo = *(const bf16x8*)(L + 65536 + row * 2048 + ((kc ^ row) << 4));
                aO = __builtin_amdgcn_mfma_f32_16x16x32_bf16(af[ks], wo, aO, 0, 0, 0);
            }
        }

        // epilogue ledger: [E_next(12), h(4), OUT(4)] -> vmcnt(4) retires E+h
        if (s < NSTEP) { // E_next for step s+1 (issued first = oldest)
            float en0[4], en1[4], en2[4];
#pragma unroll
            for (int r = 0; r < 4; ++r) {
                const float* eb = E + (long)tokv[r] * 3072 + j;
                gloadf(en0[r], eb);
                gloadf(en1[r], eb + 1024);
                gloadf(en2[r], eb + 2048);
            }
            u16* hdst = Hx + (size_t)((s + 1) & 1) * 262144;
#pragma unroll
            for (int r = 0; r < 4; ++r) { // GRU gates -> h_{s+1}
                float rg = fsigmoid(ec0[r] + zi0[r] + a0[r]);
                float zg = fsigmoid(ec1[r] + zi1[r] + a1[r]);
                float nn = ftanh(ec2[r] + zi2[r] + rg * (a2[r] + bhn));
                float hv = (1.f - zg) * nn + zg * hprev[r];
                hprev[r] = hv;
                gstore_short_c(hdst + (bbase + r) * 1024 + j, (u32)f2bf(hv));
            }
            if (s >= 1) {
#pragma unroll
                for (int r = 0; r < 4; ++r)
                    gstoref(out + (long)(bbase + r) * 131072 + (long)(s - 1) * 1024 + j,
                            aO[r] + zo[r]);
                asm volatile("s_waitcnt vmcnt(4)" ::: "memory"); // E+h done, OUT in flight
            } else {
                asm volatile("s_waitcnt vmcnt(0)" ::: "memory");
            }
            __builtin_amdgcn_sched_barrier(0);
            if (lane == 0) // arrival: this wave's h_{s+1} is at the coherent point
                (void)__hip_atomic_fetch_add(cnt + bid, 1u, __ATOMIC_RELAXED,
                                             __HIP_MEMORY_SCOPE_AGENT);
            // E regs -> current (values resident; next poll drains their loads)
#pragma unroll
            for (int r = 0; r < 4; ++r) {
                ec0[r] = en0[r];
                ec1[r] = en1[r];
                ec2[r] = en2[r];
            }
        } else { // s == NSTEP: final OUT only; dispatch end drains
#pragma unroll
            for (int r = 0; r < 4; ++r)
                gstoref(out + (long)(bbase + r) * 131072 + (long)(s - 1) * 1024 + j,
                        aO[r] + zo[r]);
        }
    }
}

extern "C" void kernel_launch(void* const* d_in, const int* in_sizes, int n_in,
                              void* d_out, int out_size, void* d_ws, size_t ws_size,
                              hipStream_t stream) {
    const float* z = (const float*)d_in[0];
    const int* toks = (const int*)d_in[1];
    const float* embed_w = (const float*)d_in[3];
    const float* z2h_w = (const float*)d_in[4];
    const float* z2h_b = (const float*)d_in[5];
    const float* w_ih = (const float*)d_in[6];
    const float* b_ih = (const float*)d_in[7];
    const float* w_hh = (const float*)d_in[8];
    const float* b_hh = (const float*)d_in[9];
    const float* out_w = (const float*)d_in[10];
    const float* out_b = (const float*)d_in[11];
    float* out = (float*)d_out;

    char* ws = (char*)d_ws;
    size_t off = 0;
    auto alloc = [&](size_t bytes) {
        char* p = ws + off;
        off += (bytes + 255) & ~(size_t)255;
        return p;
    };
    u16* Whh_bf = (u16*)alloc(3072ull * 1024 * 2);
    u16* Wout_bf = (u16*)alloc(1024ull * 1024 * 2);
    u16* Wihh_bf = (u16*)alloc(3072ull * 1024 * 2);
    u16* Emb_bf = (u16*)alloc(1024ull * 1024 * 2);
    float* E = (float*)alloc(1024ull * 3072 * 4);
    float* Zih = (float*)alloc(256ull * 3072 * 4);
    float* Zout = (float*)alloc(256ull * 1024 * 4);
    float* hf = (float*)alloc(256ull * 1024 * 4);
    u16* Hx = (u16*)alloc(2ull * 256 * 1024 * 2);
    u32* cnt = (u32*)alloc(1024);
    // total ws use ~34.5 MB

    hipMemsetAsync(cnt, 0, 1024, stream);
    cast_k<<<2048, 256, 0, stream>>>(w_hh, 1024, 0, 0, Whh_bf, 3072 * 1024);
    cast_k<<<2048, 256, 0, stream>>>(out_w, 1152, 0, 0, Wout_bf, 1024 * 1024);
    cast_k<<<2048, 256, 0, stream>>>(w_ih, 1152, 0, 0, Wihh_bf, 3072 * 1024);
    cast_k<<<1024, 256, 0, stream>>>(embed_w, 1024, 0, 1, Emb_bf, 1024 * 1024);
    smallgemm_k<<<1024, 256, 0, stream>>>(z, z2h_w, 128, 0, z2h_b, nullptr, 0, hf, Hx, 1024);
    smallgemm_k<<<3072, 256, 0, stream>>>(z, w_ih, 1152, 1024, b_ih, b_hh, 2048, Zih, nullptr, 3072);
    smallgemm_k<<<1024, 256, 0, stream>>>(z, out_w, 1152, 1024, out_b, nullptr, 0, Zout, nullptr, 1024);
    egemm_k<<<768, 256, 0, stream>>>(Emb_bf, Wihh_bf, E);

    decoder_k<<<256, 256, 0, stream>>>(Whh_bf, Wout_bf, E, Zih, Zout, b_hh, toks, hf, Hx, out,
                                       cnt);
}

// Round 11
// 1122.920 us; speedup vs baseline: 2.1193x; 2.1193x over previous
//
#include <hip/hip_runtime.h>
#include <stdint.h>

// DecoderRNN: B=256, NSTEPS=128, I=128, H=1024, V=1024, teacher-forced GRU.
// Round 11: r8 structure EXACTLY (coop staging, 4-deep dbuf, block barriers,
// per-block flags, wave0 poll) + two proven deltas:
//   (1) E prefetched one step ahead (asm ledger; en->ec copy after it7's
//       vmcnt(0), sched_barrier-pinned) -> E off the iter-0 critical path.
//   (2) fast exp2/rcp sigmoid+tanh (absmax-verified in r9/r10).
// All counted VMEM ops are inline asm -> exact vmcnt ledger.

#define NSTEP 128

typedef unsigned short u16;
typedef unsigned int u32;
typedef __attribute__((ext_vector_type(8))) short bf16x8;
typedef __attribute__((ext_vector_type(4))) int i32x4;
typedef __attribute__((ext_vector_type(4))) float f32x4;

typedef __attribute__((address_space(3))) void lds_void;
typedef const __attribute__((address_space(1))) void glb_void;
#define GLD16(g, l) __builtin_amdgcn_global_load_lds((glb_void*)(g), (lds_void*)(l), 16, 0, 0)
// CPol gfx940+: SC0=1, SC1=16 -> 17 (coherent, bypass stale L1/L2)
#define GLD16C(g, l) __builtin_amdgcn_global_load_lds((glb_void*)(g), (lds_void*)(l), 16, 0, 17)
#define CFENCE() asm volatile("" ::: "memory")
#define SCHEDB() __builtin_amdgcn_sched_barrier(0)

#if __has_builtin(__builtin_amdgcn_exp2f)
#define EXP2(x) __builtin_amdgcn_exp2f(x)
#else
#define EXP2(x) exp2f(x)
#endif
#if __has_builtin(__builtin_amdgcn_rcpf)
#define RCP(x) __builtin_amdgcn_rcpf(x)
#else
#define RCP(x) (1.0f / (x))
#endif

__device__ __forceinline__ u16 f2bf(float f) {
    u32 u = __float_as_uint(f);
    u = (u + 0x7FFFu + ((u >> 16) & 1u)) >> 16;
    return (u16)u;
}
__device__ __forceinline__ float fsigmoid(float x) {
    return RCP(1.f + EXP2(x * -1.44269504f));
}
__device__ __forceinline__ float ftanh(float x) {
    x = fminf(fmaxf(x, -18.f), 18.f);
    float t = EXP2(x * 2.88539008f);
    return (t - 1.f) * RCP(t + 1.f);
}

// ---- exact-count asm memory ops (ledger discipline) -------------------------
__device__ __forceinline__ void gloadf(float& d, const float* a) { // 1 event
    asm volatile("global_load_dword %0, %1, off" : "=&v"(d) : "v"(a) : "memory");
}
__device__ __forceinline__ void gloadi4(i32x4& d, const int* a) { // 1 event
    asm volatile("global_load_dwordx4 %0, %1, off" : "=&v"(d) : "v"(a) : "memory");
}
__device__ __forceinline__ void gstore_short_c(u16* a, u32 v) { // 1 event, coherent
    asm volatile("global_store_short %0, %1, off sc0 sc1" ::"v"(a), "v"(v) : "memory");
}
__device__ __forceinline__ void gstoref(float* a, float v) { // 1 event
    asm volatile("global_store_dword %0, %1, off" ::"v"(a), "v"(v) : "memory");
}

// ---- elementwise fp32 -> bf16 cast (1024 columns per row) ------------------
__global__ void cast_k(const float* __restrict__ src, int ld, int off, int relu,
                       u16* __restrict__ dst, int n) {
    for (int i = blockIdx.x * blockDim.x + threadIdx.x; i < n; i += gridDim.x * blockDim.x) {
        int row = i >> 10, col = i & 1023;
        float v = src[(long)row * ld + off + col];
        if (relu) v = fmaxf(v, 0.f);
        dst[i] = f2bf(v);
    }
}

// ---- small fp32 GEMM: C[b][n] = z[b]·W[n, off:off+128] + bias[n] (+bias2) --
__global__ void smallgemm_k(const float* __restrict__ z, const float* __restrict__ W,
                            int ldw, int off, const float* __restrict__ bias,
                            const float* __restrict__ bias2, int n2max,
                            float* __restrict__ C, u16* __restrict__ Cbf, int N) {
    int n = blockIdx.x;
    int b = threadIdx.x;
    float acc = bias[n] + ((bias2 && n < n2max) ? bias2[n] : 0.f);
    const float* zr = z + b * 128;
    const float* wr = W + (long)n * ldw + off;
#pragma unroll 8
    for (int k = 0; k < 128; ++k) acc += zr[k] * wr[k];
    C[b * N + n] = acc;
    if (Cbf) Cbf[b * N + n] = f2bf(acc);
}

// ---- E table GEMM: E[v][n] = relu(embed)[v]·Wihh[n]  (M=1024,N=3072,K=1024)
__global__ __launch_bounds__(256) void egemm_k(const u16* __restrict__ A,
                                               const u16* __restrict__ W,
                                               float* __restrict__ C) {
    __shared__ __align__(16) u16 lds[2][160 * 64];
    int tid = threadIdx.x, lane = tid & 63, wv = tid >> 6;
    int r0 = (blockIdx.x & 31) * 32;
    int n0 = (blockIdx.x >> 5) * 128;

    f32x4 acc[2][2];
#pragma unroll
    for (int m = 0; m < 2; ++m)
#pragma unroll
        for (int n = 0; n < 2; ++n) acc[m][n] = (f32x4){0.f, 0.f, 0.f, 0.f};

    auto stage = [&](int k0, int bufi) {
#pragma unroll
        for (int r = 0; r < 5; ++r) {
            int L = r * 256 + tid;
            int row = L >> 3;
            int c4 = (L & 7) ^ (row & 7);
            const u16* src = (row < 32)
                                 ? A + (long)(r0 + row) * 1024 + k0 + c4 * 8
                                 : W + (long)(n0 + row - 32) * 1024 + k0 + c4 * 8;
            GLD16(src, &lds[bufi][L * 8]);
        }
    };
    stage(0, 0);
    stage(64, 1);
    for (int it = 0; it < 16; ++it) {
        if (it < 15) asm volatile("s_waitcnt vmcnt(5)" ::: "memory");
        else         asm volatile("s_waitcnt vmcnt(0)" ::: "memory");
        __builtin_amdgcn_s_barrier();
        const char* base = (const char*)&lds[it & 1][0];
        bf16x8 af[2][2], bfr[2][2];
#pragma unroll
        for (int ks = 0; ks < 2; ++ks)
#pragma unroll
            for (int q = 0; q < 2; ++q) {
                int kb = ks * 64 + ((lane >> 4) << 4);
                int rowa = q * 16 + (lane & 15);
                af[ks][q] = *(const bf16x8*)(base + rowa * 128 + (kb ^ ((rowa & 7) << 4)));
                int rowb = 32 + wv * 32 + q * 16 + (lane & 15);
                bfr[ks][q] = *(const bf16x8*)(base + rowb * 128 + (kb ^ ((rowb & 7) << 4)));
            }
#pragma unroll
        for (int ks = 0; ks < 2; ++ks)
#pragma unroll
            for (int m = 0; m < 2; ++m)
#pragma unroll
                for (int n = 0; n < 2; ++n)
                    acc[m][n] = __builtin_amdgcn_mfma_f32_16x16x32_bf16(af[ks][m], bfr[ks][n],
                                                                        acc[m][n], 0, 0, 0);
        asm volatile("s_waitcnt lgkmcnt(0)" ::: "memory");
        __builtin_amdgcn_s_barrier();
        if (it + 2 < 16) stage((it + 2) * 64, it & 1);
    }
#pragma unroll
    for (int m = 0; m < 2; ++m)
#pragma unroll
        for (int n = 0; n < 2; ++n)
#pragma unroll
            for (int r = 0; r < 4; ++r) {
                int row = r0 + m * 16 + ((lane >> 4) << 2) + r;
                int col = n0 + wv * 32 + n * 16 + (lane & 15);
                C[(long)row * 3072 + col] = acc[m][n][r];
            }
}

// ---- persistent decoder ----------------------------------------------------
// LDS layout (bytes), 163840 total (full 160 KiB):
//   [0, 65536)         W12: gates z,n  [32 rows][1024 k], row stride 2048 B
//   [65536, 98304)     WoutL: [16 rows][1024 k], row stride 2048 B (persistent)
//   [98304, 163840)    dbuf: 4 x 16384 B: [64 rows][128 k], row stride 256 B
//   (startup: gate-r slice [16][1024] temporarily in dbuf region -> regs)
__global__ __launch_bounds__(256, 1) void decoder_k(
    const u16* __restrict__ Whh,    // [3072][1024] bf16
    const u16* __restrict__ Wout,   // [1024][1024] bf16
    const float* __restrict__ E,    // [1024][3072]
    const float* __restrict__ Zih2, // [256][3072]  (b_ih folded; +b_hh for r,z)
    const float* __restrict__ Zout, // [256][1024]  (out_b folded)
    const float* __restrict__ bhh,  // [3072]
    const int* __restrict__ toks,   // [128][256]
    const float* __restrict__ h0f,  // [256][1024] fp32
    u16* __restrict__ Hx,           // [2][256][1024] bf16 ping-pong
    float* __restrict__ out,        // [256][128][1024]
    u32* __restrict__ flags) {      // [256] per-block step flags
    __shared__ __align__(16) char L[163840];
    const int tid = threadIdx.x, lane = tid & 63, wv = tid >> 6;
    const int bid = blockIdx.x;
    const int rB = bid >> 6; // rows rB*64..+63
    const int c = bid & 63;  // cols c*16..+15

    // ---- startup staging: gate-r -> tmp(dbuf), gates z,n -> W12, Wout -> WoutL
#pragma unroll
    for (int r = 0; r < 8; ++r) {
        int l = r * 256 + tid, row = l >> 7, ck = (l & 127) ^ (row & 15);
        GLD16(Whh + (long)(c * 16 + row) * 1024 + ck * 8, &L[98304 + l * 16]);
    }
#pragma unroll
    for (int r = 0; r < 16; ++r) {
        int l = r * 256 + tid, row = l >> 7, ck = (l & 127) ^ (row & 15);
        GLD16(Whh + (long)((1 + (row >> 4)) * 1024 + c * 16 + (row & 15)) * 1024 + ck * 8,
              &L[l * 16]);
    }
#pragma unroll
    for (int r = 0; r < 8; ++r) {
        int l = r * 256 + tid, row = l >> 7, ck = (l & 127) ^ (row & 15);
        GLD16(Wout + (long)(c * 16 + row) * 1024 + ck * 8, &L[65536 + l * 16]);
    }
    asm volatile("s_waitcnt vmcnt(0)" ::: "memory");
    __builtin_amdgcn_s_barrier();
    bf16x8 w0[32]; // gate-r B-fragments, [it*4+ks], persistent in VGPRs
#pragma unroll
    for (int it = 0; it < 8; ++it)
#pragma unroll
        for (int ks = 0; ks < 4; ++ks) {
            int row = lane & 15, kc = it * 16 + ks * 4 + (lane >> 4);
            w0[it * 4 + ks] = *(const bf16x8*)(L + 98304 + row * 2048 + ((kc ^ row) << 4));
        }
    asm volatile("s_waitcnt lgkmcnt(0)" ::: "memory");
    __builtin_amdgcn_s_barrier();

    // ---- per-thread step-invariant state
    const int bbase = rB * 64 + wv * 16 + ((lane >> 4) << 2); // 4 rows bbase..+3
    const int j = c * 16 + (lane & 15);
    const float bhn = bhh[2048 + j];
    float hprev[4], zi0[4], zi1[4], zi2[4], zo[4];
#pragma unroll
    for (int r = 0; r < 4; ++r) {
        int b = bbase + r;
        hprev[r] = h0f[b * 1024 + j];
        zi0[r] = Zih2[(long)b * 3072 + j];
        zi1[r] = Zih2[(long)b * 3072 + 1024 + j];
        zi2[r] = Zih2[(long)b * 3072 + 2048 + j];
        zo[r] = Zout[b * 1024 + j];
    }

    // E prefetch registers: en = in-flight (asm outputs), ec = current (safe)
    float ec0[4], ec1[4], ec2[4], en0[4], en1[4], en2[4];
    // prologue: E rows for step 0 (tok = SOS = 0) -> en (12 events)
#pragma unroll
    for (int r = 0; r < 4; ++r) {
        const float* eb = E + j;
        gloadf(en0[r], eb);
        gloadf(en1[r], eb + 1024);
        gloadf(en2[r], eb + 2048);
    }

    for (int s = 0; s <= NSTEP; ++s) {
        // tok for step s+1 (1 event; oldest -> retired with stage0 at iter 0)
        i32x4 tokv;
        if (s < NSTEP) gloadi4(tokv, toks + s * 256 + bbase);

        const u16* hsrc = Hx + (size_t)(s & 1) * 262144;
        auto stage = [&](int ch) { // 4 events each
            char* dst = L + 98304 + (ch & 3) * 16384;
            int k0 = ch * 128;
#pragma unroll
            for (int r = 0; r < 4; ++r) {
                int l = r * 256 + tid, row = l >> 4, ck = (l & 15) ^ (row & 15);
                GLD16C(hsrc + (long)(rB * 64 + row) * 1024 + k0 + ck * 8, dst + l * 16);
            }
        };
        stage(0);
        stage(1);
        stage(2);
        stage(3);
        CFENCE();

        f32x4 a0 = {0.f, 0.f, 0.f, 0.f}, a1 = a0, a2 = a0, aO = a0;
#pragma unroll
        for (int it = 0; it < 8; ++it) {
            // ledger: leftovers [OUT<=4, E(12), tok(1)] are all OLDER than
            // stage0 -> waits below are exact for stages, conservative extra
            if (it < 5)       asm volatile("s_waitcnt vmcnt(12)" ::: "memory");
            else if (it == 5) asm volatile("s_waitcnt vmcnt(8)" ::: "memory");
            else if (it == 6) asm volatile("s_waitcnt vmcnt(4)" ::: "memory");
            else              asm volatile("s_waitcnt vmcnt(0)" ::: "memory");
            SCHEDB(); // rule 18: pin everything below the wait
            __builtin_amdgcn_s_barrier();
            const char* Ab = L + 98304 + (it & 3) * 16384;
            bf16x8 af[4];
#pragma unroll
            for (int ks = 0; ks < 4; ++ks) {
                int row = wv * 16 + (lane & 15), kc = ks * 4 + (lane >> 4);
                af[ks] = *(const bf16x8*)(Ab + row * 256 + ((kc ^ (row & 15)) << 4));
            }
#pragma unroll
            for (int ks = 0; ks < 4; ++ks) // gate r from registers
                a0 = __builtin_amdgcn_mfma_f32_16x16x32_bf16(af[ks], w0[it * 4 + ks], a0, 0, 0, 0);
#pragma unroll
            for (int ks = 0; ks < 4; ++ks) { // gate z from W12
                int row = lane & 15, kc = it * 16 + ks * 4 + (lane >> 4);
                bf16x8 wg = *(const bf16x8*)(L + row * 2048 + ((kc ^ row) << 4));
                a1 = __builtin_amdgcn_mfma_f32_16x16x32_bf16(af[ks], wg, a1, 0, 0, 0);
            }
#pragma unroll
            for (int ks = 0; ks < 4; ++ks) { // gate n from W12
                int row = 16 + (lane & 15), kc = it * 16 + ks * 4 + (lane >> 4);
                bf16x8 wg = *(const bf16x8*)(L + row * 2048 + ((kc ^ (row & 15)) << 4));
                a2 = __builtin_amdgcn_mfma_f32_16x16x32_bf16(af[ks], wg, a2, 0, 0, 0);
            }
#pragma unroll
            for (int ks = 0; ks < 4; ++ks) { // OUT from WoutL (persistent)
                int row = lane & 15, kc = it * 16 + ks * 4 + (lane >> 4);
                bf16x8 wo = *(const bf16x8*)(L + 65536 + row * 2048 + ((kc ^ row) << 4));
                aO = __builtin_amdgcn_mfma_f32_16x16x32_bf16(af[ks], wo, aO, 0, 0, 0);
            }
            asm volatile("s_waitcnt lgkmcnt(0)" ::: "memory");
            __builtin_amdgcn_s_barrier();
            if (it < 4) stage(it + 4);
        }
        // here: it7 did vmcnt(0)+SCHEDB -> en loads provably retired; copy
        if (s < NSTEP) {
#pragma unroll
            for (int r = 0; r < 4; ++r) {
                ec0[r] = en0[r];
                ec1[r] = en1[r];
                ec2[r] = en2[r];
            }
        }

        if (s < NSTEP) { // GRU epilogue -> h_{s+1} (ec resident; coherent stores)
            u16* hdst = Hx + (size_t)((s + 1) & 1) * 262144;
#pragma unroll
            for (int r = 0; r < 4; ++r) {
                float rg = fsigmoid(ec0[r] + zi0[r] + a0[r]);
                float zg = fsigmoid(ec1[r] + zi1[r] + a1[r]);
                float nn = ftanh(ec2[r] + zi2[r] + rg * (a2[r] + bhn));
                float hv = (1.f - zg) * nn + zg * hprev[r];
                hprev[r] = hv;
                gstore_short_c(hdst + (bbase + r) * 1024 + j, (u32)f2bf(hv));
            }
        }
        if (s >= 1) { // OUT epilogue (4 events; drain during flag poll)
#pragma unroll
            for (int r = 0; r < 4; ++r)
                gstoref(out + (long)(bbase + r) * 131072 + (long)(s - 1) * 1024 + j,
                        aO[r] + zo[r]);
        }
        if (s < NSTEP) {
            // E_next for step s+1 -> en (12 events; tokv resident since it7's
            // vmcnt(0)). Issued after h+OUT so the exchange wait can leave
            // them in flight; they retire during the poll / next K-loop.
#pragma unroll
            for (int r = 0; r < 4; ++r) {
                const float* eb = E + (long)tokv[r] * 3072 + j;
                gloadf(en0[r], eb);
                gloadf(en1[r], eb + 1024);
                gloadf(en2[r], eb + 2048);
            }
            // exchange: queue = [h(4), OUT(0|4), E(12)]; retire h only
            if (s >= 1) asm volatile("s_waitcnt vmcnt(16)" ::: "memory");
            else        asm volatile("s_waitcnt vmcnt(12)" ::: "memory");
            SCHEDB();
            __builtin_amdgcn_s_barrier();
            if (tid < 64) { // wave 0
                if (tid == 0)
                    __hip_atomic_store(&flags[bid], (u32)(s + 1), __ATOMIC_RELAXED,
                                       __HIP_MEMORY_SCOPE_AGENT);
                const u32 tgt = (u32)(s + 1);
                const u32* gf = flags + (rB << 6);
                while (true) {
                    u32 v = __hip_atomic_load(&gf[tid], __ATOMIC_RELAXED,
                                              __HIP_MEMORY_SCOPE_AGENT);
                    if (__all(v >= tgt)) break;
                    __builtin_amdgcn_s_sleep(1);
                }
            }
            __builtin_amdgcn_s_barrier();
        }
    }
}

extern "C" void kernel_launch(void* const* d_in, const int* in_sizes, int n_in,
                              void* d_out, int out_size, void* d_ws, size_t ws_size,
                              hipStream_t stream) {
    const float* z = (const float*)d_in[0];
    const int* toks = (const int*)d_in[1];
    const float* embed_w = (const float*)d_in[3];
    const float* z2h_w = (const float*)d_in[4];
    const float* z2h_b = (const float*)d_in[5];
    const float* w_ih = (const float*)d_in[6];
    const float* b_ih = (const float*)d_in[7];
    const float* w_hh = (const float*)d_in[8];
    const float* b_hh = (const float*)d_in[9];
    const float* out_w = (const float*)d_in[10];
    const float* out_b = (const float*)d_in[11];
    float* out = (float*)d_out;

    char* ws = (char*)d_ws;
    size_t off = 0;
    auto alloc = [&](size_t bytes) {
        char* p = ws + off;
        off += (bytes + 255) & ~(size_t)255;
        return p;
    };
    u16* Whh_bf = (u16*)alloc(3072ull * 1024 * 2);
    u16* Wout_bf = (u16*)alloc(1024ull * 1024 * 2);
    u16* Wihh_bf = (u16*)alloc(3072ull * 1024 * 2);
    u16* Emb_bf = (u16*)alloc(1024ull * 1024 * 2);
    float* E = (float*)alloc(1024ull * 3072 * 4);
    float* Zih = (float*)alloc(256ull * 3072 * 4);
    float* Zout = (float*)alloc(256ull * 1024 * 4);
    float* hf = (float*)alloc(256ull * 1024 * 4);
    u16* Hx = (u16*)alloc(2ull * 256 * 1024 * 2);
    u32* flags = (u32*)alloc(1024);
    // total ws use ~34.5 MB

    hipMemsetAsync(flags, 0, 1024, stream);
    cast_k<<<2048, 256, 0, stream>>>(w_hh, 1024, 0, 0, Whh_bf, 3072 * 1024);
    cast_k<<<2048, 256, 0, stream>>>(out_w, 1152, 0, 0, Wout_bf, 1024 * 1024);
    cast_k<<<2048, 256, 0, stream>>>(w_ih, 1152, 0, 0, Wihh_bf, 3072 * 1024);
    cast_k<<<1024, 256, 0, stream>>>(embed_w, 1024, 0, 1, Emb_bf, 1024 * 1024);
    smallgemm_k<<<1024, 256, 0, stream>>>(z, z2h_w, 128, 0, z2h_b, nullptr, 0, hf, Hx, 1024);
    smallgemm_k<<<3072, 256, 0, stream>>>(z, w_ih, 1152, 1024, b_ih, b_hh, 2048, Zih, nullptr, 3072);
    smallgemm_k<<<1024, 256, 0, stream>>>(z, out_w, 1152, 1024, out_b, nullptr, 0, Zout, nullptr, 1024);
    egemm_k<<<768, 256, 0, stream>>>(Emb_bf, Wihh_bf, E);

    decoder_k<<<256, 256, 0, stream>>>(Whh_bf, Wout_bf, E, Zih, Zout, b_hh, toks, hf, Hx, out,
                                       flags);
}

// Round 12
// 1116.927 us; speedup vs baseline: 2.1307x; 1.0054x over previous
//
#include <hip/hip_runtime.h>
#include <stdint.h>

// DecoderRNN: B=256, NSTEPS=128, I=128, H=1024, V=1024, teacher-forced GRU.
// Round 12: r11 skeleton + (1) gate-z weights in registers (w1[32]),
// (2) 6-deep dbuf + ONE barrier per K-iter (stage->vmcnt->barrier->read;
// hazard matrix verified for skew<=1), (3) split poll A (c0..31, step end) /
// poll B (c32..63, next step top) so poll B covers stage0-3 LLC latency.
// All counted VMEM ops inline asm -> exact vmcnt ledger.
//   LDS 160KB: [0,32K) W12n gate-n; [32K,64K) WoutL; [64K,160K) dbuf 6x16KB.
//   Registers: gate-r w0[32], gate-z w1[32] (256 VGPR), E dbl-buffer ec/en.

#define NSTEP 128

typedef unsigned short u16;
typedef unsigned int u32;
typedef __attribute__((ext_vector_type(8))) short bf16x8;
typedef __attribute__((ext_vector_type(4))) int i32x4;
typedef __attribute__((ext_vector_type(4))) float f32x4;

typedef __attribute__((address_space(3))) void lds_void;
typedef const __attribute__((address_space(1))) void glb_void;
#define GLD16(g, l) __builtin_amdgcn_global_load_lds((glb_void*)(g), (lds_void*)(l), 16, 0, 0)
// CPol gfx940+: SC0=1, SC1=16 -> 17 (coherent, bypass stale L1/L2)
#define GLD16C(g, l) __builtin_amdgcn_global_load_lds((glb_void*)(g), (lds_void*)(l), 16, 0, 17)
#define CFENCE() asm volatile("" ::: "memory")
#define SCHEDB() __builtin_amdgcn_sched_barrier(0)

#if __has_builtin(__builtin_amdgcn_exp2f)
#define EXP2(x) __builtin_amdgcn_exp2f(x)
#else
#define EXP2(x) exp2f(x)
#endif
#if __has_builtin(__builtin_amdgcn_rcpf)
#define RCP(x) __builtin_amdgcn_rcpf(x)
#else
#define RCP(x) (1.0f / (x))
#endif

__device__ __forceinline__ u16 f2bf(float f) {
    u32 u = __float_as_uint(f);
    u = (u + 0x7FFFu + ((u >> 16) & 1u)) >> 16;
    return (u16)u;
}
__device__ __forceinline__ float fsigmoid(float x) {
    return RCP(1.f + EXP2(x * -1.44269504f));
}
__device__ __forceinline__ float ftanh(float x) {
    x = fminf(fmaxf(x, -18.f), 18.f);
    float t = EXP2(x * 2.88539008f);
    return (t - 1.f) * RCP(t + 1.f);
}

// ---- exact-count asm memory ops (ledger discipline) -------------------------
__device__ __forceinline__ void gloadf(float& d, const float* a) { // 1 event
    asm volatile("global_load_dword %0, %1, off" : "=&v"(d) : "v"(a) : "memory");
}
__device__ __forceinline__ void gloadi4(i32x4& d, const int* a) { // 1 event
    asm volatile("global_load_dwordx4 %0, %1, off" : "=&v"(d) : "v"(a) : "memory");
}
__device__ __forceinline__ void gstore_short_c(u16* a, u32 v) { // 1 event, coherent
    asm volatile("global_store_short %0, %1, off sc0 sc1" ::"v"(a), "v"(v) : "memory");
}
__device__ __forceinline__ void gstoref(float* a, float v) { // 1 event
    asm volatile("global_store_dword %0, %1, off" ::"v"(a), "v"(v) : "memory");
}

// ---- elementwise fp32 -> bf16 cast (1024 columns per row) ------------------
__global__ void cast_k(const float* __restrict__ src, int ld, int off, int relu,
                       u16* __restrict__ dst, int n) {
    for (int i = blockIdx.x * blockDim.x + threadIdx.x; i < n; i += gridDim.x * blockDim.x) {
        int row = i >> 10, col = i & 1023;
        float v = src[(long)row * ld + off + col];
        if (relu) v = fmaxf(v, 0.f);
        dst[i] = f2bf(v);
    }
}

// ---- small fp32 GEMM: C[b][n] = z[b]·W[n, off:off+128] + bias[n] (+bias2) --
__global__ void smallgemm_k(const float* __restrict__ z, const float* __restrict__ W,
                            int ldw, int off, const float* __restrict__ bias,
                            const float* __restrict__ bias2, int n2max,
                            float* __restrict__ C, u16* __restrict__ Cbf, int N) {
    int n = blockIdx.x;
    int b = threadIdx.x;
    float acc = bias[n] + ((bias2 && n < n2max) ? bias2[n] : 0.f);
    const float* zr = z + b * 128;
    const float* wr = W + (long)n * ldw + off;
#pragma unroll 8
    for (int k = 0; k < 128; ++k) acc += zr[k] * wr[k];
    C[b * N + n] = acc;
    if (Cbf) Cbf[b * N + n] = f2bf(acc);
}

// ---- E table GEMM: E[v][n] = relu(embed)[v]·Wihh[n]  (M=1024,N=3072,K=1024)
__global__ __launch_bounds__(256) void egemm_k(const u16* __restrict__ A,
                                               const u16* __restrict__ W,
                                               float* __restrict__ C) {
    __shared__ __align__(16) u16 lds[2][160 * 64];
    int tid = threadIdx.x, lane = tid & 63, wv = tid >> 6;
    int r0 = (blockIdx.x & 31) * 32;
    int n0 = (blockIdx.x >> 5) * 128;

    f32x4 acc[2][2];
#pragma unroll
    for (int m = 0; m < 2; ++m)
#pragma unroll
        for (int n = 0; n < 2; ++n) acc[m][n] = (f32x4){0.f, 0.f, 0.f, 0.f};

    auto stage = [&](int k0, int bufi) {
#pragma unroll
        for (int r = 0; r < 5; ++r) {
            int L = r * 256 + tid;
            int row = L >> 3;
            int c4 = (L & 7) ^ (row & 7);
            const u16* src = (row < 32)
                                 ? A + (long)(r0 + row) * 1024 + k0 + c4 * 8
                                 : W + (long)(n0 + row - 32) * 1024 + k0 + c4 * 8;
            GLD16(src, &lds[bufi][L * 8]);
        }
    };
    stage(0, 0);
    stage(64, 1);
    for (int it = 0; it < 16; ++it) {
        if (it < 15) asm volatile("s_waitcnt vmcnt(5)" ::: "memory");
        else         asm volatile("s_waitcnt vmcnt(0)" ::: "memory");
        __builtin_amdgcn_s_barrier();
        const char* base = (const char*)&lds[it & 1][0];
        bf16x8 af[2][2], bfr[2][2];
#pragma unroll
        for (int ks = 0; ks < 2; ++ks)
#pragma unroll
            for (int q = 0; q < 2; ++q) {
                int kb = ks * 64 + ((lane >> 4) << 4);
                int rowa = q * 16 + (lane & 15);
                af[ks][q] = *(const bf16x8*)(base + rowa * 128 + (kb ^ ((rowa & 7) << 4)));
                int rowb = 32 + wv * 32 + q * 16 + (lane & 15);
                bfr[ks][q] = *(const bf16x8*)(base + rowb * 128 + (kb ^ ((rowb & 7) << 4)));
            }
#pragma unroll
        for (int ks = 0; ks < 2; ++ks)
#pragma unroll
            for (int m = 0; m < 2; ++m)
#pragma unroll
                for (int n = 0; n < 2; ++n)
                    acc[m][n] = __builtin_amdgcn_mfma_f32_16x16x32_bf16(af[ks][m], bfr[ks][n],
                                                                        acc[m][n], 0, 0, 0);
        asm volatile("s_waitcnt lgkmcnt(0)" ::: "memory");
        __builtin_amdgcn_s_barrier();
        if (it + 2 < 16) stage((it + 2) * 64, it & 1);
    }
#pragma unroll
    for (int m = 0; m < 2; ++m)
#pragma unroll
        for (int n = 0; n < 2; ++n)
#pragma unroll
            for (int r = 0; r < 4; ++r) {
                int row = r0 + m * 16 + ((lane >> 4) << 2) + r;
                int col = n0 + wv * 32 + n * 16 + (lane & 15);
                C[(long)row * 3072 + col] = acc[m][n][r];
            }
}

// ---- persistent decoder ----------------------------------------------------
// LDS layout (bytes), 163840 total:
//   [0, 32768)        W12n: gate n  [16 rows][1024 k], row stride 2048 B
//   [32768, 65536)    WoutL: [16 rows][1024 k], row stride 2048 B
//   [65536, 163840)   dbuf: 6 x 16384 B: [64 rows][128 k], row stride 256 B
//   (startup: gate-r temp at 65536, gate-z temp at 98304 -> regs)
__global__ __launch_bounds__(256, 1) void decoder_k(
    const u16* __restrict__ Whh,    // [3072][1024] bf16
    const u16* __restrict__ Wout,   // [1024][1024] bf16
    const float* __restrict__ E,    // [1024][3072]
    const float* __restrict__ Zih2, // [256][3072]  (b_ih folded; +b_hh for r,z)
    const float* __restrict__ Zout, // [256][1024]  (out_b folded)
    const float* __restrict__ bhh,  // [3072]
    const int* __restrict__ toks,   // [128][256]
    const float* __restrict__ h0f,  // [256][1024] fp32
    u16* __restrict__ Hx,           // [2][256][1024] bf16 ping-pong
    float* __restrict__ out,        // [256][128][1024]
    u32* __restrict__ flags) {      // [256] per-block step flags
    __shared__ __align__(16) char L[163840];
    const int tid = threadIdx.x, lane = tid & 63, wv = tid >> 6;
    const int bid = blockIdx.x;
    const int rB = bid >> 6; // rows rB*64..+63
    const int c = bid & 63;  // cols c*16..+15

    // ---- startup: gate-r -> temp@65536, gate-z -> temp@98304 -> registers
#pragma unroll
    for (int r = 0; r < 8; ++r) {
        int l = r * 256 + tid, row = l >> 7, ck = (l & 127) ^ (row & 15);
        GLD16(Whh + (long)(c * 16 + row) * 1024 + ck * 8, &L[65536 + l * 16]);
    }
#pragma unroll
    for (int r = 0; r < 8; ++r) {
        int l = r * 256 + tid, row = l >> 7, ck = (l & 127) ^ (row & 15);
        GLD16(Whh + (long)(1024 + c * 16 + row) * 1024 + ck * 8, &L[98304 + l * 16]);
    }
    asm volatile("s_waitcnt vmcnt(0)" ::: "memory");
    __builtin_amdgcn_s_barrier();
    bf16x8 w0[32], w1[32]; // gate-r / gate-z B-fragments [it*4+ks]
#pragma unroll
    for (int it = 0; it < 8; ++it)
#pragma unroll
        for (int ks = 0; ks < 4; ++ks) {
            int row = lane & 15, kc = it * 16 + ks * 4 + (lane >> 4);
            w0[it * 4 + ks] = *(const bf16x8*)(L + 65536 + row * 2048 + ((kc ^ row) << 4));
            w1[it * 4 + ks] = *(const bf16x8*)(L + 98304 + row * 2048 + ((kc ^ row) << 4));
        }
    asm volatile("s_waitcnt lgkmcnt(0)" ::: "memory");
    __builtin_amdgcn_s_barrier();
    // gate-n -> W12n [0,32K), Wout -> WoutL [32K,64K)
#pragma unroll
    for (int r = 0; r < 8; ++r) {
        int l = r * 256 + tid, row = l >> 7, ck = (l & 127) ^ (row & 15);
        GLD16(Whh + (long)(2048 + c * 16 + row) * 1024 + ck * 8, &L[l * 16]);
    }
#pragma unroll
    for (int r = 0; r < 8; ++r) {
        int l = r * 256 + tid, row = l >> 7, ck = (l & 127) ^ (row & 15);
        GLD16(Wout + (long)(c * 16 + row) * 1024 + ck * 8, &L[32768 + l * 16]);
    }
    asm volatile("s_waitcnt vmcnt(0)" ::: "memory");
    __builtin_amdgcn_s_barrier();

    // ---- per-thread step-invariant state
    const int bbase = rB * 64 + wv * 16 + ((lane >> 4) << 2); // 4 rows bbase..+3
    const int j = c * 16 + (lane & 15);
    const float bhn = bhh[2048 + j];
    float hprev[4], zi0[4], zi1[4], zi2[4], zo[4];
#pragma unroll
    for (int r = 0; r < 4; ++r) {
        int b = bbase + r;
        hprev[r] = h0f[b * 1024 + j];
        zi0[r] = Zih2[(long)b * 3072 + j];
        zi1[r] = Zih2[(long)b * 3072 + 1024 + j];
        zi2[r] = Zih2[(long)b * 3072 + 2048 + j];
        zo[r] = Zout[b * 1024 + j];
    }

    float ec0[4], ec1[4], ec2[4], en0[4], en1[4], en2[4];
    // prologue: E rows for step 0 (tok = SOS = 0) -> en (12 events)
#pragma unroll
    for (int r = 0; r < 4; ++r) {
        const float* eb = E + j;
        gloadf(en0[r], eb);
        gloadf(en1[r], eb + 1024);
        gloadf(en2[r], eb + 2048);
    }

    for (int s = 0; s <= NSTEP; ++s) {
        // tok for step s+1 (1 event; older than stage0 -> ledger-neutral)
        i32x4 tokv;
        if (s < NSTEP) gloadi4(tokv, toks + s * 256 + bbase);

        const u16* hsrc = Hx + (size_t)(s & 1) * 262144;
        auto stage = [&](int ch) { // 4 events each; buf = ch mod 6
            char* dst = L + 65536 + (ch % 6) * 16384;
            int k0 = ch * 128;
#pragma unroll
            for (int r = 0; r < 4; ++r) {
                int l = r * 256 + tid, row = l >> 4, ck = (l & 15) ^ (row & 15);
                GLD16C(hsrc + (long)(rB * 64 + row) * 1024 + k0 + ck * 8, dst + l * 16);
            }
        };
        stage(0);
        stage(1);
        stage(2);
        stage(3);
        CFENCE();

        if (s >= 1) { // poll B: producers c32..63 (gate chunks 4-7); its LLC
                      // round trip covers stage0-3 flight time
            if (tid < 64) {
                const u32 tgt = (u32)s;
                const u32* gf = flags + (rB << 6) + 32;
                while (true) {
                    u32 v = __hip_atomic_load(gf + (lane & 31), __ATOMIC_RELAXED,
                                              __HIP_MEMORY_SCOPE_AGENT);
                    if (__all(v >= tgt)) break;
                    __builtin_amdgcn_s_sleep(1);
                }
            }
            __builtin_amdgcn_s_barrier();
        }

        f32x4 a0 = {0.f, 0.f, 0.f, 0.f}, a1 = a0, a2 = a0, aO = a0;
#pragma unroll
        for (int it = 0; it < 8; ++it) {
            if (it < 4) stage(it + 4); // writes buf (it+4)%6: safe vs skew<=1
            // ledger: newer-than-stage(it) = 4 stages (it+1..it+4) for it<4
            if (it < 4)       asm volatile("s_waitcnt vmcnt(16)" ::: "memory");
            else if (it == 4) asm volatile("s_waitcnt vmcnt(12)" ::: "memory");
            else if (it == 5) asm volatile("s_waitcnt vmcnt(8)" ::: "memory");
            else if (it == 6) asm volatile("s_waitcnt vmcnt(4)" ::: "memory");
            else              asm volatile("s_waitcnt vmcnt(0)" ::: "memory");
            SCHEDB();
            __builtin_amdgcn_s_barrier(); // all waves' chunk-it loads landed
            const char* Ab = L + 65536 + (it % 6) * 16384;
            bf16x8 af[4];
#pragma unroll
            for (int ks = 0; ks < 4; ++ks) {
                int row = wv * 16 + (lane & 15), kc = ks * 4 + (lane >> 4);
                af[ks] = *(const bf16x8*)(Ab + row * 256 + ((kc ^ (row & 15)) << 4));
            }
#pragma unroll
            for (int ks = 0; ks < 4; ++ks) // gate r from registers
                a0 = __builtin_amdgcn_mfma_f32_16x16x32_bf16(af[ks], w0[it * 4 + ks], a0, 0, 0, 0);
#pragma unroll
            for (int ks = 0; ks < 4; ++ks) // gate z from registers
                a1 = __builtin_amdgcn_mfma_f32_16x16x32_bf16(af[ks], w1[it * 4 + ks], a1, 0, 0, 0);
#pragma unroll
            for (int ks = 0; ks < 4; ++ks) { // gate n from W12n
                int row = lane & 15, kc = it * 16 + ks * 4 + (lane >> 4);
                bf16x8 wg = *(const bf16x8*)(L + row * 2048 + ((kc ^ row) << 4));
                a2 = __builtin_amdgcn_mfma_f32_16x16x32_bf16(af[ks], wg, a2, 0, 0, 0);
            }
#pragma unroll
            for (int ks = 0; ks < 4; ++ks) { // OUT from WoutL
                int row = lane & 15, kc = it * 16 + ks * 4 + (lane >> 4);
                bf16x8 wo = *(const bf16x8*)(L + 32768 + row * 2048 + ((kc ^ row) << 4));
                aO = __builtin_amdgcn_mfma_f32_16x16x32_bf16(af[ks], wo, aO, 0, 0, 0);
            }
            // no trailing barrier: 6-buf rotation + top barrier cover hazards
        }
        // it7 did vmcnt(0)+SCHEDB -> en loads provably retired; copy
        if (s < NSTEP) {
#pragma unroll
            for (int r = 0; r < 4; ++r) {
                ec0[r] = en0[r];
                ec1[r] = en1[r];
                ec2[r] = en2[r];
            }
        }

        if (s < NSTEP) { // GRU epilogue -> h_{s+1} (coherent stores)
            u16* hdst = Hx + (size_t)((s + 1) & 1) * 262144;
#pragma unroll
            for (int r = 0; r < 4; ++r) {
                float rg = fsigmoid(ec0[r] + zi0[r] + a0[r]);
                float zg = fsigmoid(ec1[r] + zi1[r] + a1[r]);
                float nn = ftanh(ec2[r] + zi2[r] + rg * (a2[r] + bhn));
                float hv = (1.f - zg) * nn + zg * hprev[r];
                hprev[r] = hv;
                gstore_short_c(hdst + (bbase + r) * 1024 + j, (u32)f2bf(hv));
            }
        }
        if (s >= 1) { // OUT epilogue (4 events; drain during poll)
#pragma unroll
            for (int r = 0; r < 4; ++r)
                gstoref(out + (long)(bbase + r) * 131072 + (long)(s - 1) * 1024 + j,
                        aO[r] + zo[r]);
        }
        if (s < NSTEP) {
            // E_next for step s+1 -> en (12 events, newest)
#pragma unroll
            for (int r = 0; r < 4; ++r) {
                const float* eb = E + (long)tokv[r] * 3072 + j;
                gloadf(en0[r], eb);
                gloadf(en1[r], eb + 1024);
                gloadf(en2[r], eb + 2048);
            }
            // exchange: queue = [h(4), OUT(0|4), E(12)]; retire h only
            if (s >= 1) asm volatile("s_waitcnt vmcnt(16)" ::: "memory");
            else        asm volatile("s_waitcnt vmcnt(12)" ::: "memory");
            SCHEDB();
            __builtin_amdgcn_s_barrier();
            if (tid == 0)
                __hip_atomic_store(&flags[bid], (u32)(s + 1), __ATOMIC_RELAXED,
                                   __HIP_MEMORY_SCOPE_AGENT);
            if (tid < 64) { // poll A: producers c0..31 (gate next chunks 0-3)
                const u32 tgt = (u32)(s + 1);
                const u32* gf = flags + (rB << 6);
                while (true) {
                    u32 v = __hip_atomic_load(gf + (lane & 31), __ATOMIC_RELAXED,
                                              __HIP_MEMORY_SCOPE_AGENT);
                    if (__all(v >= tgt)) break;
                    __builtin_amdgcn_s_sleep(1);
                }
            }
            __builtin_amdgcn_s_barrier();
        }
    }
}

extern "C" void kernel_launch(void* const* d_in, const int* in_sizes, int n_in,
                              void* d_out, int out_size, void* d_ws, size_t ws_size,
                              hipStream_t stream) {
    const float* z = (const float*)d_in[0];
    const int* toks = (const int*)d_in[1];
    const float* embed_w = (const float*)d_in[3];
    const float* z2h_w = (const float*)d_in[4];
    const float* z2h_b = (const float*)d_in[5];
    const float* w_ih = (const float*)d_in[6];
    const float* b_ih = (const float*)d_in[7];
    const float* w_hh = (const float*)d_in[8];
    const float* b_hh = (const float*)d_in[9];
    const float* out_w = (const float*)d_in[10];
    const float* out_b = (const float*)d_in[11];
    float* out = (float*)d_out;

    char* ws = (char*)d_ws;
    size_t off = 0;
    auto alloc = [&](size_t bytes) {
        char* p = ws + off;
        off += (bytes + 255) & ~(size_t)255;
        return p;
    };
    u16* Whh_bf = (u16*)alloc(3072ull * 1024 * 2);
    u16* Wout_bf = (u16*)alloc(1024ull * 1024 * 2);
    u16* Wihh_bf = (u16*)alloc(3072ull * 1024 * 2);
    u16* Emb_bf = (u16*)alloc(1024ull * 1024 * 2);
    float* E = (float*)alloc(1024ull * 3072 * 4);
    float* Zih = (float*)alloc(256ull * 3072 * 4);
    float* Zout = (float*)alloc(256ull * 1024 * 4);
    float* hf = (float*)alloc(256ull * 1024 * 4);
    u16* Hx = (u16*)alloc(2ull * 256 * 1024 * 2);
    u32* flags = (u32*)alloc(1024);
    // total ws use ~34.5 MB

    hipMemsetAsync(flags, 0, 1024, stream);
    cast_k<<<2048, 256, 0, stream>>>(w_hh, 1024, 0, 0, Whh_bf, 3072 * 1024);
    cast_k<<<2048, 256, 0, stream>>>(out_w, 1152, 0, 0, Wout_bf, 1024 * 1024);
    cast_k<<<2048, 256, 0, stream>>>(w_ih, 1152, 0, 0, Wihh_bf, 3072 * 1024);
    cast_k<<<1024, 256, 0, stream>>>(embed_w, 1024, 0, 1, Emb_bf, 1024 * 1024);
    smallgemm_k<<<1024, 256, 0, stream>>>(z, z2h_w, 128, 0, z2h_b, nullptr, 0, hf, Hx, 1024);
    smallgemm_k<<<3072, 256, 0, stream>>>(z, w_ih, 1152, 1024, b_ih, b_hh, 2048, Zih, nullptr, 3072);
    smallgemm_k<<<1024, 256, 0, stream>>>(z, out_w, 1152, 1024, out_b, nullptr, 0, Zout, nullptr, 1024);
    egemm_k<<<768, 256, 0, stream>>>(Emb_bf, Wihh_bf, E);

    decoder_k<<<256, 256, 0, stream>>>(Whh_bf, Wout_bf, E, Zih, Zout, b_hh, toks, hf, Hx, out,
                                       flags);
}